// Round 3
// baseline (30817.599 us; speedup 1.0000x reference)
//
#include <hip/hip_runtime.h>
#include <cstdint>
#include <cstddef>

#define N_OBJ 2048
#define N_TOT 2064
#define NUM_CLASSES 151
#define EMBED 200
#define HID 512
#define OBJ_DIM 4096
#define POS 128
#define OBJ_IN 4424   // 4096+200+128
#define DEC_IN 4936   // 512+4424
#define EDGE_IN 4808  // 200+4096+512
#define G4 2048       // 4*HID
#define NROLE 128     // scan blocks (1 wave each), 4 h-dims per role
#define SPIN_LIMIT 30000

// ----------------------------------------------------------------------------
// utility kernels
// ----------------------------------------------------------------------------
__global__ void init_flags_kernel(unsigned* flags, int n) {
  int i = blockIdx.x * blockDim.x + threadIdx.x;
  if (i < n) flags[i] = 0u;
}

__global__ void copy4_kernel(const float4* __restrict__ src, float4* __restrict__ dst, long n4) {
  long i = blockIdx.x * (long)blockDim.x + threadIdx.x;
  long stride = (long)gridDim.x * blockDim.x;
  for (; i < n4; i += stride) dst[i] = src[i];
}

// feats[r][0:4096] = x[r]
__global__ void copy_x_kernel(const float* __restrict__ x, float* __restrict__ feats) {
  long i = blockIdx.x * (long)blockDim.x + threadIdx.x; // over 2048*1024 float4
  if (i >= (long)N_OBJ * (OBJ_DIM / 4)) return;
  long r = i >> 10, c = i & 1023;
  reinterpret_cast<float4*>(feats + r * (long)OBJ_IN)[c] =
      reinterpret_cast<const float4*>(x + r * (long)OBJ_DIM)[c];
}

// feats[r][4096:4296] = obj_dists_in[r] @ embed1
__global__ void obj_embed_kernel(const float* __restrict__ dists,
                                 const float* __restrict__ embed1,
                                 float* __restrict__ feats) {
  int r = blockIdx.x;
  __shared__ float drow[NUM_CLASSES];
  for (int c = threadIdx.x; c < NUM_CLASSES; c += blockDim.x)
    drow[c] = dists[(size_t)r * NUM_CLASSES + c];
  __syncthreads();
  for (int j = threadIdx.x; j < EMBED; j += blockDim.x) {
    float s = 0.f;
    for (int k = 0; k < NUM_CLASSES; ++k)
      s = fmaf(drow[k], embed1[(size_t)k * EMBED + j], s);
    feats[(size_t)r * OBJ_IN + OBJ_DIM + j] = s;
  }
}

// feats[r][4296:4424] = relu(BN(box@W1+b1)@W2+b2)
__global__ void pos_kernel(const float* __restrict__ box,
                           const float* __restrict__ W1, const float* __restrict__ b1,
                           const float* __restrict__ gamma, const float* __restrict__ beta,
                           const float* __restrict__ mean, const float* __restrict__ var,
                           const float* __restrict__ W2, const float* __restrict__ b2,
                           float* __restrict__ feats) {
  int r = blockIdx.x;
  __shared__ float h[32];
  __shared__ float bx[9];
  if (threadIdx.x < 9) bx[threadIdx.x] = box[(size_t)r * 9 + threadIdx.x];
  __syncthreads();
  if (threadIdx.x < 32) {
    float s = b1[threadIdx.x];
    for (int k = 0; k < 9; ++k) s = fmaf(bx[k], W1[k * 32 + threadIdx.x], s);
    s = (s - mean[threadIdx.x]) * (1.f / sqrtf(var[threadIdx.x] + 1e-5f)) * gamma[threadIdx.x]
        + beta[threadIdx.x];
    h[threadIdx.x] = s;
  }
  __syncthreads();
  int j = threadIdx.x;
  if (j < POS) {
    float s = b2[j];
    for (int k = 0; k < 32; ++k) s = fmaf(h[k], W2[k * POS + j], s);
    feats[(size_t)r * OBJ_IN + OBJ_DIM + EMBED + j] = fmaxf(s, 0.f);
  }
}

// ----------------------------------------------------------------------------
// generic bounds-checked fp32 GEMM: C[M,N](ldc) = A[M,K](lda) @ B[K,N](ldb) (+bias | +=)
// tile 64x64, BK=16, 256 threads, 4x4 per thread
// ----------------------------------------------------------------------------
template <int ACC>
__global__ __launch_bounds__(256)
void gemm_kernel(const float* __restrict__ A, int lda,
                 const float* __restrict__ B, int ldb,
                 const float* __restrict__ bias,
                 float* __restrict__ C, int ldc,
                 int M, int N, int K) {
  __shared__ __align__(16) float As[16][68];
  __shared__ __align__(16) float Bs[16][64];
  const int row0 = blockIdx.y * 64;
  const int col0 = blockIdx.x * 64;
  const int tid = threadIdx.x;
  const int tx = tid & 15, ty = tid >> 4;
  float acc[4][4] = {};

  for (int k0 = 0; k0 < K; k0 += 16) {
#pragma unroll
    for (int l = 0; l < 4; ++l) {
      int idx = tid + l * 256;
      int m = idx >> 4, kk = idx & 15;
      int gm = row0 + m, gk = k0 + kk;
      As[kk][m] = (gm < M && gk < K) ? A[(size_t)gm * lda + gk] : 0.f;
    }
#pragma unroll
    for (int l = 0; l < 4; ++l) {
      int idx = tid + l * 256;
      int kk = idx >> 6, n = idx & 63;
      int gk = k0 + kk, gn = col0 + n;
      Bs[kk][n] = (gk < K && gn < N) ? B[(size_t)gk * ldb + gn] : 0.f;
    }
    __syncthreads();
#pragma unroll
    for (int kk = 0; kk < 16; ++kk) {
      float4 a = *reinterpret_cast<const float4*>(&As[kk][ty * 4]);
      float4 b = *reinterpret_cast<const float4*>(&Bs[kk][tx * 4]);
      acc[0][0] = fmaf(a.x, b.x, acc[0][0]); acc[0][1] = fmaf(a.x, b.y, acc[0][1]);
      acc[0][2] = fmaf(a.x, b.z, acc[0][2]); acc[0][3] = fmaf(a.x, b.w, acc[0][3]);
      acc[1][0] = fmaf(a.y, b.x, acc[1][0]); acc[1][1] = fmaf(a.y, b.y, acc[1][1]);
      acc[1][2] = fmaf(a.y, b.z, acc[1][2]); acc[1][3] = fmaf(a.y, b.w, acc[1][3]);
      acc[2][0] = fmaf(a.z, b.x, acc[2][0]); acc[2][1] = fmaf(a.z, b.y, acc[2][1]);
      acc[2][2] = fmaf(a.z, b.z, acc[2][2]); acc[2][3] = fmaf(a.z, b.w, acc[2][3]);
      acc[3][0] = fmaf(a.w, b.x, acc[3][0]); acc[3][1] = fmaf(a.w, b.y, acc[3][1]);
      acc[3][2] = fmaf(a.w, b.z, acc[3][2]); acc[3][3] = fmaf(a.w, b.w, acc[3][3]);
    }
    __syncthreads();
  }
#pragma unroll
  for (int i = 0; i < 4; ++i) {
    int gm = row0 + ty * 4 + i;
    if (gm >= M) continue;
#pragma unroll
    for (int j = 0; j < 4; ++j) {
      int gn = col0 + tx * 4 + j;
      if (gn >= N) continue;
      size_t o = (size_t)gm * ldc + gn;
      if (ACC) C[o] += acc[i][j];
      else C[o] = acc[i][j] + (bias ? bias[gn] : 0.f);
    }
  }
}

// ----------------------------------------------------------------------------
// persistent LSTM scan, latency-optimized:
//   128 blocks x 1 wave (64 threads). Block r owns h-dims [4r, 4r+4).
//   Its 16 Wh columns (16 x 512 fp32 = 32 KB) are staged in LDS once.
//   Lane l: col q=l>>2 (dim q>>2, gate q&3), k-quarter qt=l&3 (128 k each).
//   Per step: poll 128 flags (relaxed sc1) -> load h (relaxed sc1) -> LDS ->
//   dot (ds_read_b128, conflict-free) -> shfl reduce -> gates via shfl ->
//   h store (sc1) -> s_waitcnt vmcnt(0) -> flag store. No __syncthreads, no
//   acquire/release cache maintenance anywhere.
// ----------------------------------------------------------------------------
__global__ __launch_bounds__(64, 1)
void lstm_scan_kernel(const float* __restrict__ pre,  // T x 2048
                      const float* __restrict__ Wh,   // 512 x 2048
                      float* __restrict__ hs,         // T x 512
                      float* hg,                      // 2*512 exchange buffer
                      unsigned* flags,                // NROLE flags, zeroed
                      int T) {
  __shared__ float4 w4[32][64];                 // [k4][lane] 32 KB
  __shared__ __align__(16) float hlp[532];      // 4 segments of 128, +4 pad each
  const int l = threadIdx.x;
  const int r = blockIdx.x;                     // role 0..127
  const int d0 = r * 4;
  const int q = l >> 2;                         // 0..15: col within role
  const int qt = l & 3;                         // k-quarter
  const int dq = q >> 2;                        // 0..3 dim
  const int gq = q & 3;                         // gate
  const int col = gq * HID + d0 + dq;           // Wh column

  // stage this lane's 128 weights into LDS (once)
  {
    const float* base = Wh + (size_t)(qt * 128) * G4 + col;
#pragma unroll
    for (int j4 = 0; j4 < 32; ++j4) {
      float4 t;
      t.x = base[(size_t)(4 * j4 + 0) * G4];
      t.y = base[(size_t)(4 * j4 + 1) * G4];
      t.z = base[(size_t)(4 * j4 + 2) * G4];
      t.w = base[(size_t)(4 * j4 + 3) * G4];
      w4[j4][l] = t;
    }
  }
  // zero h in LDS (h_{-1} = 0)
  for (int i = l; i < 532; i += 64) hlp[i] = 0.f;

  float creg = 0.f;
  bool dead = false;

  for (int s = 0; s < T; ++s) {
    // independent of h: prefetch pre-activation for this col (overlaps poll)
    float pre_v = pre[(size_t)s * G4 + col];

    if (s > 0) {
      if (!dead) {
        int tries = 0;
        for (;;) {
          unsigned f0 = __hip_atomic_load(&flags[l], __ATOMIC_RELAXED,
                                          __HIP_MEMORY_SCOPE_AGENT);
          unsigned f1 = __hip_atomic_load(&flags[64 + l], __ATOMIC_RELAXED,
                                          __HIP_MEMORY_SCOPE_AGENT);
          if (__all(f0 >= (unsigned)s && f1 >= (unsigned)s)) break;
          if (++tries > SPIN_LIMIT) { dead = true; break; }
          __builtin_amdgcn_s_sleep(1);
        }
      }
      asm volatile("" ::: "memory");  // no reordering of h loads above the poll
      // load h (512 floats; lane l takes 8) from coherence point, stage to LDS
      const float* hsrc = hg + ((s - 1) & 1) * HID + l * 8;
      float hv[8];
#pragma unroll
      for (int j = 0; j < 8; ++j)
        hv[j] = __hip_atomic_load(hsrc + j, __ATOMIC_RELAXED, __HIP_MEMORY_SCOPE_AGENT);
      const int idx = l * 8;
      const int p0 = idx + 4 * (idx >> 7);  // segment padding (+4 per 128)
#pragma unroll
      for (int j = 0; j < 8; ++j) hlp[p0 + j] = hv[j];
    }

    // dot: this lane's quarter of its column
    float acc = 0.f;
    const float* hseg = &hlp[132 * qt];
#pragma unroll
    for (int j4 = 0; j4 < 32; ++j4) {
      float4 wv = w4[j4][l];
      float4 hv4 = *reinterpret_cast<const float4*>(&hseg[4 * j4]);
      acc = fmaf(wv.x, hv4.x, acc);
      acc = fmaf(wv.y, hv4.y, acc);
      acc = fmaf(wv.z, hv4.z, acc);
      acc = fmaf(wv.w, hv4.w, acc);
    }
    // combine quarters -> all 4 lanes of col q hold the full dot
    acc += __shfl_xor(acc, 1);
    acc += __shfl_xor(acc, 2);
    float full = acc + pre_v;

    // gather the 4 gate values for this lane's dim (group of 16 lanes)
    int gbase = (l & 48) | (l & 3);
    float vi = __shfl(full, gbase | 0);
    float vf = __shfl(full, gbase | 4);
    float vg = __shfl(full, gbase | 8);
    float vo = __shfl(full, gbase | 12);

    float si = 1.f / (1.f + __expf(-vi));
    float sf = 1.f / (1.f + __expf(-vf));
    float so = 1.f / (1.f + __expf(-vo));
    creg = sf * creg + si * tanhf(vg);
    float h = so * tanhf(creg);

    if ((l & 15) == 0) {
      int dim = d0 + (l >> 4);
      hs[(size_t)s * HID + dim] = h;
      __hip_atomic_store(&hg[(s & 1) * HID + dim], h, __ATOMIC_RELAXED,
                         __HIP_MEMORY_SCOPE_AGENT);
    }
    // h stores acked at coherence point before flag store issues
    asm volatile("s_waitcnt vmcnt(0)" ::: "memory");
    __builtin_amdgcn_sched_barrier(0);
    if (l == 0)
      __hip_atomic_store(&flags[r], (unsigned)(s + 1), __ATOMIC_RELAXED,
                         __HIP_MEMORY_SCOPE_AGENT);
  }
}

// ----------------------------------------------------------------------------
// argmax over 151 logits per row (first-occurrence semantics), one wave per row
// ----------------------------------------------------------------------------
__global__ void argmax_kernel(const float* __restrict__ dists, int* __restrict__ pred_i,
                              float* __restrict__ pred_f) {
  int r = blockIdx.x;
  int lane = threadIdx.x;
  float bv = -3.4e38f;
  int bi = NUM_CLASSES;
  for (int cc = lane; cc < NUM_CLASSES; cc += 64) {
    float v = dists[(size_t)r * NUM_CLASSES + cc];
    if (v > bv) { bv = v; bi = cc; }
  }
  for (int off = 32; off; off >>= 1) {
    float ov = __shfl_xor(bv, off);
    int oi = __shfl_xor(bi, off);
    if (ov > bv || (ov == bv && oi < bi)) { bv = ov; bi = oi; }
  }
  if (lane == 0) {
    pred_i[r] = bi;
    pred_f[r] = (float)bi;
  }
}

// edge_feats[r] = [embed2[pred[r]] | x[r] | enc[r]] (r<2048) else virtual_edge[r-2048]
__global__ void build_edge_kernel(const float* __restrict__ embed2, const int* __restrict__ pred,
                                  const float* __restrict__ x, const float* __restrict__ enc,
                                  const float* __restrict__ vedge, float* __restrict__ out) {
  int r = blockIdx.x;
  float* dst = out + (size_t)r * EDGE_IN;
  if (r >= N_OBJ) {
    const float* src = vedge + (size_t)(r - N_OBJ) * EDGE_IN;
    for (int cc = threadIdx.x; cc < EDGE_IN; cc += blockDim.x) dst[cc] = src[cc];
  } else {
    const float* e = embed2 + (size_t)pred[r] * EMBED;
    for (int cc = threadIdx.x; cc < EMBED; cc += blockDim.x) dst[cc] = e[cc];
    const float* xr = x + (size_t)r * OBJ_DIM;
    for (int cc = threadIdx.x; cc < OBJ_DIM; cc += blockDim.x) dst[EMBED + cc] = xr[cc];
    const float* er = enc + (size_t)r * HID;
    for (int cc = threadIdx.x; cc < HID; cc += blockDim.x) dst[EMBED + OBJ_DIM + cc] = er[cc];
  }
}

// ----------------------------------------------------------------------------
extern "C" void kernel_launch(void* const* d_in, const int* in_sizes, int n_in,
                              void* d_out, int out_size, void* d_ws, size_t ws_size,
                              hipStream_t stream) {
  const float* x        = (const float*)d_in[0];
  const float* odists   = (const float*)d_in[1];
  const float* box      = (const float*)d_in[2];
  const float* vobj     = (const float*)d_in[3];
  const float* vedge    = (const float*)d_in[4];
  const float* embed1   = (const float*)d_in[5];
  const float* embed2   = (const float*)d_in[6];
  const float* pos_W1   = (const float*)d_in[7];
  const float* pos_b1   = (const float*)d_in[8];
  const float* bn_gamma = (const float*)d_in[9];
  const float* bn_beta  = (const float*)d_in[10];
  const float* bn_mean  = (const float*)d_in[11];
  const float* bn_var   = (const float*)d_in[12];
  const float* pos_W2   = (const float*)d_in[13];
  const float* pos_b2   = (const float*)d_in[14];
  const float* obj_Wi   = (const float*)d_in[15];
  const float* obj_Wh   = (const float*)d_in[16];
  const float* obj_b    = (const float*)d_in[17];
  const float* dec_Wi   = (const float*)d_in[18];
  const float* dec_Wh   = (const float*)d_in[19];
  const float* dec_b    = (const float*)d_in[20];
  const float* out_W    = (const float*)d_in[21];
  const float* out_b    = (const float*)d_in[22];
  const float* edge_Wi  = (const float*)d_in[23];
  const float* edge_Wh  = (const float*)d_in[24];
  const float* edge_b   = (const float*)d_in[25];

  float* out = (float*)d_out;

  // workspace layout (floats) — edgeh aliases dech (logits GEMM completes first)
  float* bigA  = (float*)d_ws;                          // 2064x4808 max
  float* pre   = bigA + (size_t)N_TOT * EDGE_IN;        // 2064x2048
  float* enc   = pre + (size_t)N_TOT * G4;              // 2064x512
  float* dech  = enc + (size_t)N_TOT * HID;             // 2064x512 (also edgeh)
  float* hg    = dech + (size_t)N_TOT * HID;            // 2x512
  int* pred_i  = (int*)(hg + 2 * HID);                  // 2048
  unsigned* flags = (unsigned*)(pred_i + N_OBJ);        // 3*NROLE

  const size_t need_bytes =
      ((size_t)N_TOT * EDGE_IN + (size_t)N_TOT * G4 + 2 * (size_t)N_TOT * HID + 2 * HID) * 4 +
      (size_t)N_OBJ * 4 + 3 * NROLE * 4 + 256;
  if (ws_size < need_bytes) return;  // insufficient scratch: fail loudly, don't corrupt

  const size_t OUT_PRED = (size_t)N_OBJ * NUM_CLASSES;  // 309248
  const size_t OUT_EDGE = OUT_PRED + N_OBJ;             // 311296

  init_flags_kernel<<<(3 * NROLE + 255) / 256, 256, 0, stream>>>(flags, 3 * NROLE);

  // build feats
  copy_x_kernel<<<(N_OBJ * (OBJ_DIM / 4) + 255) / 256, 256, 0, stream>>>(x, bigA);
  {
    long n4 = (long)16 * OBJ_IN / 4;
    copy4_kernel<<<(unsigned)((n4 + 255) / 256), 256, 0, stream>>>(
        (const float4*)vobj, (float4*)(bigA + (size_t)N_OBJ * OBJ_IN), n4);
  }
  obj_embed_kernel<<<N_OBJ, 256, 0, stream>>>(odists, embed1, bigA);
  pos_kernel<<<N_OBJ, 128, 0, stream>>>(box, pos_W1, pos_b1, bn_gamma, bn_beta, bn_mean,
                                        bn_var, pos_W2, pos_b2, bigA);

  // encoder LSTM
  gemm_kernel<0><<<dim3(32, 33), 256, 0, stream>>>(bigA, OBJ_IN, obj_Wi, G4, obj_b,
                                                   pre, G4, N_TOT, G4, OBJ_IN);
  lstm_scan_kernel<<<NROLE, 64, 0, stream>>>(pre, obj_Wh, enc, hg, flags + 0 * NROLE, N_TOT);

  // decoder LSTM (input = [feats | enc], done as two GEMMs)
  gemm_kernel<0><<<dim3(32, 33), 256, 0, stream>>>(bigA, OBJ_IN, dec_Wi, G4, dec_b,
                                                   pre, G4, N_TOT, G4, OBJ_IN);
  gemm_kernel<1><<<dim3(32, 33), 256, 0, stream>>>(enc, HID, dec_Wi + (size_t)OBJ_IN * G4, G4,
                                                   nullptr, pre, G4, N_TOT, G4, HID);
  lstm_scan_kernel<<<NROLE, 64, 0, stream>>>(pre, dec_Wh, dech, hg, flags + 1 * NROLE, N_TOT);

  // logits (rows 0..2047 only) straight into d_out, then argmax
  gemm_kernel<0><<<dim3(3, 32), 256, 0, stream>>>(dech, HID, out_W, NUM_CLASSES, out_b,
                                                  out, NUM_CLASSES, N_OBJ, NUM_CLASSES, HID);
  argmax_kernel<<<N_OBJ, 64, 0, stream>>>(out, pred_i, out + OUT_PRED);

  // edge LSTM (edgeh aliases dech — safe: logits GEMM already consumed dech)
  build_edge_kernel<<<N_TOT, 256, 0, stream>>>(embed2, pred_i, x, enc, vedge, bigA);
  gemm_kernel<0><<<dim3(32, 33), 256, 0, stream>>>(bigA, EDGE_IN, edge_Wi, G4, edge_b,
                                                   pre, G4, N_TOT, G4, EDGE_IN);
  lstm_scan_kernel<<<NROLE, 64, 0, stream>>>(pre, edge_Wh, dech, hg, flags + 2 * NROLE, N_TOT);

  // edge_ctx = edgeh[:2048] -> d_out
  copy4_kernel<<<1024, 256, 0, stream>>>((const float4*)dech, (float4*)(out + OUT_EDGE),
                                         (long)N_OBJ * HID / 4);
}

// Round 5
// 29841.309 us; speedup vs baseline: 1.0327x; 1.0327x over previous
//
#include <hip/hip_runtime.h>
#include <cstdint>
#include <cstddef>

#define N_OBJ 2048
#define N_TOT 2064
#define NUM_CLASSES 151
#define EMBED 200
#define HID 512
#define OBJ_DIM 4096
#define POS 128
#define OBJ_IN 4424   // 4096+200+128
#define DEC_IN 4936   // 512+4424
#define EDGE_IN 4808  // 200+4096+512
#define G4 2048       // 4*HID
#define NBLK 32       // scan blocks; 4 waves each; wave owns 4 h-dims
#define DATA_SPIN 20000

// ----------------------------------------------------------------------------
// utility kernels
// ----------------------------------------------------------------------------
__global__ void init_sync_kernel(unsigned* p, int n) {
  int i = blockIdx.x * blockDim.x + threadIdx.x;
  int stride = gridDim.x * blockDim.x;
  for (; i < n; i += stride) p[i] = 0u;
}

__global__ void copy4_kernel(const float4* __restrict__ src, float4* __restrict__ dst, long n4) {
  long i = blockIdx.x * (long)blockDim.x + threadIdx.x;
  long stride = (long)gridDim.x * blockDim.x;
  for (; i < n4; i += stride) dst[i] = src[i];
}

// feats[r][0:4096] = x[r]
__global__ void copy_x_kernel(const float* __restrict__ x, float* __restrict__ feats) {
  long i = blockIdx.x * (long)blockDim.x + threadIdx.x; // over 2048*1024 float4
  if (i >= (long)N_OBJ * (OBJ_DIM / 4)) return;
  long r = i >> 10, c = i & 1023;
  reinterpret_cast<float4*>(feats + r * (long)OBJ_IN)[c] =
      reinterpret_cast<const float4*>(x + r * (long)OBJ_DIM)[c];
}

// feats[r][4096:4296] = obj_dists_in[r] @ embed1
__global__ void obj_embed_kernel(const float* __restrict__ dists,
                                 const float* __restrict__ embed1,
                                 float* __restrict__ feats) {
  int r = blockIdx.x;
  __shared__ float drow[NUM_CLASSES];
  for (int c = threadIdx.x; c < NUM_CLASSES; c += blockDim.x)
    drow[c] = dists[(size_t)r * NUM_CLASSES + c];
  __syncthreads();
  for (int j = threadIdx.x; j < EMBED; j += blockDim.x) {
    float s = 0.f;
    for (int k = 0; k < NUM_CLASSES; ++k)
      s = fmaf(drow[k], embed1[(size_t)k * EMBED + j], s);
    feats[(size_t)r * OBJ_IN + OBJ_DIM + j] = s;
  }
}

// feats[r][4296:4424] = relu(BN(box@W1+b1)@W2+b2)
__global__ void pos_kernel(const float* __restrict__ box,
                           const float* __restrict__ W1, const float* __restrict__ b1,
                           const float* __restrict__ gamma, const float* __restrict__ beta,
                           const float* __restrict__ mean, const float* __restrict__ var,
                           const float* __restrict__ W2, const float* __restrict__ b2,
                           float* __restrict__ feats) {
  int r = blockIdx.x;
  __shared__ float h[32];
  __shared__ float bx[9];
  if (threadIdx.x < 9) bx[threadIdx.x] = box[(size_t)r * 9 + threadIdx.x];
  __syncthreads();
  if (threadIdx.x < 32) {
    float s = b1[threadIdx.x];
    for (int k = 0; k < 9; ++k) s = fmaf(bx[k], W1[k * 32 + threadIdx.x], s);
    s = (s - mean[threadIdx.x]) * (1.f / sqrtf(var[threadIdx.x] + 1e-5f)) * gamma[threadIdx.x]
        + beta[threadIdx.x];
    h[threadIdx.x] = s;
  }
  __syncthreads();
  int j = threadIdx.x;
  if (j < POS) {
    float s = b2[j];
    for (int k = 0; k < 32; ++k) s = fmaf(h[k], W2[k * POS + j], s);
    feats[(size_t)r * OBJ_IN + OBJ_DIM + EMBED + j] = fmaxf(s, 0.f);
  }
}

// ----------------------------------------------------------------------------
// generic bounds-checked fp32 GEMM: C[M,N](ldc) = A[M,K](lda) @ B[K,N](ldb) (+bias | +=)
// tile 64x64, BK=16, 256 threads, 4x4 per thread
// ----------------------------------------------------------------------------
template <int ACC>
__global__ __launch_bounds__(256)
void gemm_kernel(const float* __restrict__ A, int lda,
                 const float* __restrict__ B, int ldb,
                 const float* __restrict__ bias,
                 float* __restrict__ C, int ldc,
                 int M, int N, int K) {
  __shared__ __align__(16) float As[16][68];
  __shared__ __align__(16) float Bs[16][64];
  const int row0 = blockIdx.y * 64;
  const int col0 = blockIdx.x * 64;
  const int tid = threadIdx.x;
  const int tx = tid & 15, ty = tid >> 4;
  float acc[4][4] = {};

  for (int k0 = 0; k0 < K; k0 += 16) {
#pragma unroll
    for (int l = 0; l < 4; ++l) {
      int idx = tid + l * 256;
      int m = idx >> 4, kk = idx & 15;
      int gm = row0 + m, gk = k0 + kk;
      As[kk][m] = (gm < M && gk < K) ? A[(size_t)gm * lda + gk] : 0.f;
    }
#pragma unroll
    for (int l = 0; l < 4; ++l) {
      int idx = tid + l * 256;
      int kk = idx >> 6, n = idx & 63;
      int gk = k0 + kk, gn = col0 + n;
      Bs[kk][n] = (gk < K && gn < N) ? B[(size_t)gk * ldb + gn] : 0.f;
    }
    __syncthreads();
#pragma unroll
    for (int kk = 0; kk < 16; ++kk) {
      float4 a = *reinterpret_cast<const float4*>(&As[kk][ty * 4]);
      float4 b = *reinterpret_cast<const float4*>(&Bs[kk][tx * 4]);
      acc[0][0] = fmaf(a.x, b.x, acc[0][0]); acc[0][1] = fmaf(a.x, b.y, acc[0][1]);
      acc[0][2] = fmaf(a.x, b.z, acc[0][2]); acc[0][3] = fmaf(a.x, b.w, acc[0][3]);
      acc[1][0] = fmaf(a.y, b.x, acc[1][0]); acc[1][1] = fmaf(a.y, b.y, acc[1][1]);
      acc[1][2] = fmaf(a.y, b.z, acc[1][2]); acc[1][3] = fmaf(a.y, b.w, acc[1][3]);
      acc[2][0] = fmaf(a.z, b.x, acc[2][0]); acc[2][1] = fmaf(a.z, b.y, acc[2][1]);
      acc[2][2] = fmaf(a.z, b.z, acc[2][2]); acc[2][3] = fmaf(a.z, b.w, acc[2][3]);
      acc[3][0] = fmaf(a.w, b.x, acc[3][0]); acc[3][1] = fmaf(a.w, b.y, acc[3][1]);
      acc[3][2] = fmaf(a.w, b.z, acc[3][2]); acc[3][3] = fmaf(a.w, b.w, acc[3][3]);
    }
    __syncthreads();
  }
#pragma unroll
  for (int i = 0; i < 4; ++i) {
    int gm = row0 + ty * 4 + i;
    if (gm >= M) continue;
#pragma unroll
    for (int j = 0; j < 4; ++j) {
      int gn = col0 + tx * 4 + j;
      if (gn >= N) continue;
      size_t o = (size_t)gm * ldc + gn;
      if (ACC) C[o] += acc[i][j];
      else C[o] = acc[i][j] + (bias ? bias[gn] : 0.f);
    }
  }
}

// ----------------------------------------------------------------------------
// persistent LSTM scan: 32 blocks x 4 independent waves (no __syncthreads in
// or after the loop). Wave (blk,wv) owns h-dims [16*blk+4*wv, +4) — identical
// per-wave math to the round-3 verified kernel. Its 16 Wh columns live in LDS
// ([k4][lane], staged once). h exchange: 8-byte tagged pairs {f32 h, u32 tag
// = s+1}, double-buffered by step parity, relaxed agent-scope atomics both
// sides (the codegen path proven correct AND non-hanging in rounds 2/3).
// The tag check IS the data load: one coherence-point round trip per step.
// Lap-safety: buffer (s-1)&1 cannot be overwritten (by step s+1 stores) until
// every block has finished step s — and any block still polling hasn't.
// ----------------------------------------------------------------------------
__global__ __launch_bounds__(256, 1)
void lstm_scan_kernel(const float* __restrict__ pre,      // T x 2048
                      const float* __restrict__ Wh,       // 512 x 2048
                      float* __restrict__ hs,             // T x 512
                      unsigned long long* hg,             // 2*512 tagged pairs
                      int T) {
  __shared__ float4 w4[4][32][64];               // 128 KB: per-wave [k4][lane]
  __shared__ float hlp[4][532];                  // per-wave h copy, 4x(128+4 pad)

  const int tid = threadIdx.x;
  const int wv = tid >> 6;                       // wave 0..3
  const int l = tid & 63;

  const int q = l >> 2;                          // col within wave, 0..15
  const int qt = l & 3;                          // k-quarter (128 k each)
  const int dq = q >> 2;                         // dim within wave, 0..3
  const int gq = q & 3;                          // gate (i,f,g,o)
  const int d0w = blockIdx.x * 16 + wv * 4;      // wave's first dim
  const int colw = gq * HID + d0w + dq;          // Wh column

  // stage this wave's 16 columns into LDS (once); wave-private region
  {
    const float* base = Wh + (size_t)(qt * 128) * G4 + colw;
#pragma unroll 4
    for (int j4 = 0; j4 < 32; ++j4) {
      float4 t;
      t.x = base[(size_t)(4 * j4 + 0) * G4];
      t.y = base[(size_t)(4 * j4 + 1) * G4];
      t.z = base[(size_t)(4 * j4 + 2) * G4];
      t.w = base[(size_t)(4 * j4 + 3) * G4];
      w4[wv][j4][l] = t;
    }
  }
  for (int i = l; i < 532; i += 64) hlp[wv][i] = 0.f;  // h_{-1} = 0

  float creg = 0.f;
  bool dead = false;

  for (int s = 0; s < T; ++s) {
    // independent of h: prefetch pre-activation (overlaps the poll)
    float pre_v = pre[(size_t)s * G4 + colw];

    if (s > 0) {
      const unsigned long long* src = hg + ((s - 1) & 1) * HID + l * 8;
      unsigned long long pv[8];
      if (!dead) {
        int tries = 0;
        for (;;) {
          unsigned tmin = 0xFFFFFFFFu;
#pragma unroll
          for (int j = 0; j < 8; ++j) {
            pv[j] = __hip_atomic_load(src + j, __ATOMIC_RELAXED, __HIP_MEMORY_SCOPE_AGENT);
            tmin = min(tmin, (unsigned)(pv[j] >> 32));
          }
          if (__all((int)(tmin >= (unsigned)s))) break;          // snapshot valid
          if (++tries > DATA_SPIN) { dead = true; break; }       // loud fail, no hang
        }
      }
      if (dead) {
#pragma unroll
        for (int j = 0; j < 8; ++j) pv[j] = 0ull;
      }
      // stage h dims [8l, 8l+8) into this wave's padded LDS copy
      const int pp = 8 * l + 4 * (l >> 4);  // +4 pad per 128-segment
#pragma unroll
      for (int j = 0; j < 8; ++j) hlp[wv][pp + j] = __uint_as_float((unsigned)pv[j]);
    }

    // dot: this lane's k-quarter of its column (4 indep FMA chains)
    float a0 = 0.f, a1 = 0.f, a2 = 0.f, a3 = 0.f;
    const float* hseg = &hlp[wv][132 * qt];
#pragma unroll
    for (int j4 = 0; j4 < 32; ++j4) {
      float4 wv4 = w4[wv][j4][l];
      float4 hv4 = *reinterpret_cast<const float4*>(&hseg[4 * j4]);
      a0 = fmaf(wv4.x, hv4.x, a0);
      a1 = fmaf(wv4.y, hv4.y, a1);
      a2 = fmaf(wv4.z, hv4.z, a2);
      a3 = fmaf(wv4.w, hv4.w, a3);
    }
    float acc = (a0 + a1) + (a2 + a3);
    acc += __shfl_xor(acc, 1);
    acc += __shfl_xor(acc, 2);
    float full = acc + pre_v;

    // gather the 4 gate values for this lane's dim (16-lane group)
    int gbase = (l & 48) | (l & 3);
    float vi = __shfl(full, gbase);
    float vf = __shfl(full, gbase | 4);
    float vg = __shfl(full, gbase | 8);
    float vo = __shfl(full, gbase | 12);

    float si = 1.f / (1.f + __expf(-vi));
    float sf = 1.f / (1.f + __expf(-vf));
    float so = 1.f / (1.f + __expf(-vo));
    creg = sf * creg + si * tanhf(vg);
    float h = so * tanhf(creg);

    if ((l & 15) == 0) {
      int dim = d0w + (l >> 4);
      hs[(size_t)s * HID + dim] = h;
      unsigned long long pvs =
          ((unsigned long long)(unsigned)(s + 1) << 32) | (unsigned)__float_as_uint(h);
      __hip_atomic_store(hg + (s & 1) * HID + dim, pvs, __ATOMIC_RELAXED,
                         __HIP_MEMORY_SCOPE_AGENT);
    }
  }
}

// ----------------------------------------------------------------------------
// argmax over 151 logits per row (first-occurrence semantics), one wave per row
// ----------------------------------------------------------------------------
__global__ void argmax_kernel(const float* __restrict__ dists, int* __restrict__ pred_i,
                              float* __restrict__ pred_f) {
  int r = blockIdx.x;
  int lane = threadIdx.x;
  float bv = -3.4e38f;
  int bi = NUM_CLASSES;
  for (int cc = lane; cc < NUM_CLASSES; cc += 64) {
    float v = dists[(size_t)r * NUM_CLASSES + cc];
    if (v > bv) { bv = v; bi = cc; }
  }
  for (int off = 32; off; off >>= 1) {
    float ov = __shfl_xor(bv, off);
    int oi = __shfl_xor(bi, off);
    if (ov > bv || (ov == bv && oi < bi)) { bv = ov; bi = oi; }
  }
  if (lane == 0) {
    pred_i[r] = bi;
    pred_f[r] = (float)bi;
  }
}

// edge_feats[r] = [embed2[pred[r]] | x[r] | enc[r]] (r<2048) else virtual_edge[r-2048]
__global__ void build_edge_kernel(const float* __restrict__ embed2, const int* __restrict__ pred,
                                  const float* __restrict__ x, const float* __restrict__ enc,
                                  const float* __restrict__ vedge, float* __restrict__ out) {
  int r = blockIdx.x;
  float* dst = out + (size_t)r * EDGE_IN;
  if (r >= N_OBJ) {
    const float* src = vedge + (size_t)(r - N_OBJ) * EDGE_IN;
    for (int cc = threadIdx.x; cc < EDGE_IN; cc += blockDim.x) dst[cc] = src[cc];
  } else {
    const float* e = embed2 + (size_t)pred[r] * EMBED;
    for (int cc = threadIdx.x; cc < EMBED; cc += blockDim.x) dst[cc] = e[cc];
    const float* xr = x + (size_t)r * OBJ_DIM;
    for (int cc = threadIdx.x; cc < OBJ_DIM; cc += blockDim.x) dst[EMBED + cc] = xr[cc];
    const float* er = enc + (size_t)r * HID;
    for (int cc = threadIdx.x; cc < HID; cc += blockDim.x) dst[EMBED + OBJ_DIM + cc] = er[cc];
  }
}

// ----------------------------------------------------------------------------
extern "C" void kernel_launch(void* const* d_in, const int* in_sizes, int n_in,
                              void* d_out, int out_size, void* d_ws, size_t ws_size,
                              hipStream_t stream) {
  const float* x        = (const float*)d_in[0];
  const float* odists   = (const float*)d_in[1];
  const float* box      = (const float*)d_in[2];
  const float* vobj     = (const float*)d_in[3];
  const float* vedge    = (const float*)d_in[4];
  const float* embed1   = (const float*)d_in[5];
  const float* embed2   = (const float*)d_in[6];
  const float* pos_W1   = (const float*)d_in[7];
  const float* pos_b1   = (const float*)d_in[8];
  const float* bn_gamma = (const float*)d_in[9];
  const float* bn_beta  = (const float*)d_in[10];
  const float* bn_mean  = (const float*)d_in[11];
  const float* bn_var   = (const float*)d_in[12];
  const float* pos_W2   = (const float*)d_in[13];
  const float* pos_b2   = (const float*)d_in[14];
  const float* obj_Wi   = (const float*)d_in[15];
  const float* obj_Wh   = (const float*)d_in[16];
  const float* obj_b    = (const float*)d_in[17];
  const float* dec_Wi   = (const float*)d_in[18];
  const float* dec_Wh   = (const float*)d_in[19];
  const float* dec_b    = (const float*)d_in[20];
  const float* out_W    = (const float*)d_in[21];
  const float* out_b    = (const float*)d_in[22];
  const float* edge_Wi  = (const float*)d_in[23];
  const float* edge_Wh  = (const float*)d_in[24];
  const float* edge_b   = (const float*)d_in[25];

  float* out = (float*)d_out;

  // workspace layout — edgeh aliases dech (logits GEMM completes first)
  float* bigA = (float*)d_ws;                           // 2064x4808 max
  float* pre  = bigA + (size_t)N_TOT * EDGE_IN;         // 2064x2048
  float* enc  = pre + (size_t)N_TOT * G4;               // 2064x512
  float* dech = enc + (size_t)N_TOT * HID;              // 2064x512 (also edgeh)
  int* pred_i = (int*)(dech + (size_t)N_TOT * HID);     // 2048
  unsigned long long* hg3 = (unsigned long long*)(pred_i + N_OBJ);  // 3 x 1024 pairs

  const int SYNC_U32 = 3 * 2 * HID * 2;                 // hg3 as u32
  const size_t need_bytes =
      ((size_t)N_TOT * EDGE_IN + (size_t)N_TOT * G4 + 2 * (size_t)N_TOT * HID) * 4 +
      (size_t)N_OBJ * 4 + (size_t)SYNC_U32 * 4 + 256;
  if (ws_size < need_bytes) return;  // insufficient scratch: fail loudly, don't corrupt

  const size_t OUT_PRED = (size_t)N_OBJ * NUM_CLASSES;  // 309248
  const size_t OUT_EDGE = OUT_PRED + N_OBJ;             // 311296

  init_sync_kernel<<<8, 256, 0, stream>>>((unsigned*)hg3, SYNC_U32);

  // build feats
  copy_x_kernel<<<(N_OBJ * (OBJ_DIM / 4) + 255) / 256, 256, 0, stream>>>(x, bigA);
  {
    long n4 = (long)16 * OBJ_IN / 4;
    copy4_kernel<<<(unsigned)((n4 + 255) / 256), 256, 0, stream>>>(
        (const float4*)vobj, (float4*)(bigA + (size_t)N_OBJ * OBJ_IN), n4);
  }
  obj_embed_kernel<<<N_OBJ, 256, 0, stream>>>(odists, embed1, bigA);
  pos_kernel<<<N_OBJ, 128, 0, stream>>>(box, pos_W1, pos_b1, bn_gamma, bn_beta, bn_mean,
                                        bn_var, pos_W2, pos_b2, bigA);

  // encoder LSTM
  gemm_kernel<0><<<dim3(32, 33), 256, 0, stream>>>(bigA, OBJ_IN, obj_Wi, G4, obj_b,
                                                   pre, G4, N_TOT, G4, OBJ_IN);
  lstm_scan_kernel<<<NBLK, 256, 0, stream>>>(pre, obj_Wh, enc, hg3 + 0 * 2 * HID, N_TOT);

  // decoder LSTM (input = [feats | enc], done as two GEMMs)
  gemm_kernel<0><<<dim3(32, 33), 256, 0, stream>>>(bigA, OBJ_IN, dec_Wi, G4, dec_b,
                                                   pre, G4, N_TOT, G4, OBJ_IN);
  gemm_kernel<1><<<dim3(32, 33), 256, 0, stream>>>(enc, HID, dec_Wi + (size_t)OBJ_IN * G4, G4,
                                                   nullptr, pre, G4, N_TOT, G4, HID);
  lstm_scan_kernel<<<NBLK, 256, 0, stream>>>(pre, dec_Wh, dech, hg3 + 1 * 2 * HID, N_TOT);

  // logits (rows 0..2047 only) straight into d_out, then argmax
  gemm_kernel<0><<<dim3(3, 32), 256, 0, stream>>>(dech, HID, out_W, NUM_CLASSES, out_b,
                                                  out, NUM_CLASSES, N_OBJ, NUM_CLASSES, HID);
  argmax_kernel<<<N_OBJ, 64, 0, stream>>>(out, pred_i, out + OUT_PRED);

  // edge LSTM (edgeh aliases dech — safe: logits GEMM already consumed dech)
  build_edge_kernel<<<N_TOT, 256, 0, stream>>>(embed2, pred_i, x, enc, vedge, bigA);
  gemm_kernel<0><<<dim3(32, 33), 256, 0, stream>>>(bigA, EDGE_IN, edge_Wi, G4, edge_b,
                                                   pre, G4, N_TOT, G4, EDGE_IN);
  lstm_scan_kernel<<<NBLK, 256, 0, stream>>>(pre, edge_Wh, dech, hg3 + 2 * 2 * HID, N_TOT);

  // edge_ctx = edgeh[:2048] -> d_out
  copy4_kernel<<<1024, 256, 0, stream>>>((const float4*)dech, (float4*)(out + OUT_EDGE),
                                         (long)N_OBJ * HID / 4);
}

// Round 7
// 21831.955 us; speedup vs baseline: 1.4116x; 1.3669x over previous
//
#include <hip/hip_runtime.h>
#include <cstdint>
#include <cstddef>

#define N_OBJ 2048
#define N_TOT 2064
#define NUM_CLASSES 151
#define EMBED 200
#define HID 512
#define OBJ_DIM 4096
#define POS 128
#define OBJ_IN 4424   // 4096+200+128
#define DEC_IN 4936   // 512+4424
#define EDGE_IN 4808  // 200+4096+512
#define G4 2048       // 4*HID
#define NBLK 32       // scan blocks; 4 waves each; block owns 16 h-dims
#define DATA_SPIN 8000

// ----------------------------------------------------------------------------
// utility kernels
// ----------------------------------------------------------------------------
__global__ void init_sync_kernel(unsigned* p, int n) {
  int i = blockIdx.x * blockDim.x + threadIdx.x;
  int stride = gridDim.x * blockDim.x;
  for (; i < n; i += stride) p[i] = 0u;
}

__global__ void copy4_kernel(const float4* __restrict__ src, float4* __restrict__ dst, long n4) {
  long i = blockIdx.x * (long)blockDim.x + threadIdx.x;
  long stride = (long)gridDim.x * blockDim.x;
  for (; i < n4; i += stride) dst[i] = src[i];
}

// feats[r][0:4096] = x[r]
__global__ void copy_x_kernel(const float* __restrict__ x, float* __restrict__ feats) {
  long i = blockIdx.x * (long)blockDim.x + threadIdx.x; // over 2048*1024 float4
  if (i >= (long)N_OBJ * (OBJ_DIM / 4)) return;
  long r = i >> 10, c = i & 1023;
  reinterpret_cast<float4*>(feats + r * (long)OBJ_IN)[c] =
      reinterpret_cast<const float4*>(x + r * (long)OBJ_DIM)[c];
}

// feats[r][4096:4296] = obj_dists_in[r] @ embed1
__global__ void obj_embed_kernel(const float* __restrict__ dists,
                                 const float* __restrict__ embed1,
                                 float* __restrict__ feats) {
  int r = blockIdx.x;
  __shared__ float drow[NUM_CLASSES];
  for (int c = threadIdx.x; c < NUM_CLASSES; c += blockDim.x)
    drow[c] = dists[(size_t)r * NUM_CLASSES + c];
  __syncthreads();
  for (int j = threadIdx.x; j < EMBED; j += blockDim.x) {
    float s = 0.f;
    for (int k = 0; k < NUM_CLASSES; ++k)
      s = fmaf(drow[k], embed1[(size_t)k * EMBED + j], s);
    feats[(size_t)r * OBJ_IN + OBJ_DIM + j] = s;
  }
}

// feats[r][4296:4424] = relu(BN(box@W1+b1)@W2+b2)
__global__ void pos_kernel(const float* __restrict__ box,
                           const float* __restrict__ W1, const float* __restrict__ b1,
                           const float* __restrict__ gamma, const float* __restrict__ beta,
                           const float* __restrict__ mean, const float* __restrict__ var,
                           const float* __restrict__ W2, const float* __restrict__ b2,
                           float* __restrict__ feats) {
  int r = blockIdx.x;
  __shared__ float h[32];
  __shared__ float bx[9];
  if (threadIdx.x < 9) bx[threadIdx.x] = box[(size_t)r * 9 + threadIdx.x];
  __syncthreads();
  if (threadIdx.x < 32) {
    float s = b1[threadIdx.x];
    for (int k = 0; k < 9; ++k) s = fmaf(bx[k], W1[k * 32 + threadIdx.x], s);
    s = (s - mean[threadIdx.x]) * (1.f / sqrtf(var[threadIdx.x] + 1e-5f)) * gamma[threadIdx.x]
        + beta[threadIdx.x];
    h[threadIdx.x] = s;
  }
  __syncthreads();
  int j = threadIdx.x;
  if (j < POS) {
    float s = b2[j];
    for (int k = 0; k < 32; ++k) s = fmaf(h[k], W2[k * POS + j], s);
    feats[(size_t)r * OBJ_IN + OBJ_DIM + EMBED + j] = fmaxf(s, 0.f);
  }
}

// ----------------------------------------------------------------------------
// generic bounds-checked fp32 GEMM: C[M,N](ldc) = A[M,K](lda) @ B[K,N](ldb) (+bias | +=)
// tile 64x64, BK=16, 256 threads, 4x4 per thread
// ----------------------------------------------------------------------------
template <int ACC>
__global__ __launch_bounds__(256)
void gemm_kernel(const float* __restrict__ A, int lda,
                 const float* __restrict__ B, int ldb,
                 const float* __restrict__ bias,
                 float* __restrict__ C, int ldc,
                 int M, int N, int K) {
  __shared__ __align__(16) float As[16][68];
  __shared__ __align__(16) float Bs[16][64];
  const int row0 = blockIdx.y * 64;
  const int col0 = blockIdx.x * 64;
  const int tid = threadIdx.x;
  const int tx = tid & 15, ty = tid >> 4;
  float acc[4][4] = {};

  for (int k0 = 0; k0 < K; k0 += 16) {
#pragma unroll
    for (int l = 0; l < 4; ++l) {
      int idx = tid + l * 256;
      int m = idx >> 4, kk = idx & 15;
      int gm = row0 + m, gk = k0 + kk;
      As[kk][m] = (gm < M && gk < K) ? A[(size_t)gm * lda + gk] : 0.f;
    }
#pragma unroll
    for (int l = 0; l < 4; ++l) {
      int idx = tid + l * 256;
      int kk = idx >> 6, n = idx & 63;
      int gk = k0 + kk, gn = col0 + n;
      Bs[kk][n] = (gk < K && gn < N) ? B[(size_t)gk * ldb + gn] : 0.f;
    }
    __syncthreads();
#pragma unroll
    for (int kk = 0; kk < 16; ++kk) {
      float4 a = *reinterpret_cast<const float4*>(&As[kk][ty * 4]);
      float4 b = *reinterpret_cast<const float4*>(&Bs[kk][tx * 4]);
      acc[0][0] = fmaf(a.x, b.x, acc[0][0]); acc[0][1] = fmaf(a.x, b.y, acc[0][1]);
      acc[0][2] = fmaf(a.x, b.z, acc[0][2]); acc[0][3] = fmaf(a.x, b.w, acc[0][3]);
      acc[1][0] = fmaf(a.y, b.x, acc[1][0]); acc[1][1] = fmaf(a.y, b.y, acc[1][1]);
      acc[1][2] = fmaf(a.y, b.z, acc[1][2]); acc[1][3] = fmaf(a.y, b.w, acc[1][3]);
      acc[2][0] = fmaf(a.z, b.x, acc[2][0]); acc[2][1] = fmaf(a.z, b.y, acc[2][1]);
      acc[2][2] = fmaf(a.z, b.z, acc[2][2]); acc[2][3] = fmaf(a.z, b.w, acc[2][3]);
      acc[3][0] = fmaf(a.w, b.x, acc[3][0]); acc[3][1] = fmaf(a.w, b.y, acc[3][1]);
      acc[3][2] = fmaf(a.w, b.z, acc[3][2]); acc[3][3] = fmaf(a.w, b.w, acc[3][3]);
    }
    __syncthreads();
  }
#pragma unroll
  for (int i = 0; i < 4; ++i) {
    int gm = row0 + ty * 4 + i;
    if (gm >= M) continue;
#pragma unroll
    for (int j = 0; j < 4; ++j) {
      int gn = col0 + tx * 4 + j;
      if (gn >= N) continue;
      size_t o = (size_t)gm * ldc + gn;
      if (ACC) C[o] += acc[i][j];
      else C[o] = acc[i][j] + (bias ? bias[gn] : 0.f);
    }
  }
}

// ----------------------------------------------------------------------------
// persistent LSTM scan: 32 blocks x 4 waves. Block owns dims [16b,16b+16);
// wave wv owns dims [16b+4wv, +4). Weights in LDS ([k4][lane], staged once).
// Per-step sync (congestion-minimized):
//   producer: h stores (relaxed/agent) -> __syncthreads (drains all waves'
//   vmcnt before s_barrier; release-equivalent) -> tid0 stores flags[blk]=s+1.
//   consumer: ONLY wave 0 polls the single 128B flag line, with s_sleep(2)
//   backoff (~50ns) to keep coherence-point congestion low; on success loads
//   the 512-float h once into a block-shared LDS copy; waves 1-3 wait at
//   __syncthreads with zero memory traffic.
// Bounded spin + STICKY dead-latch: worst case is ONE ~1.3ms stall per scan
// then free-running garbage -> loud absmax failure, never a hang.
// ----------------------------------------------------------------------------
__global__ __launch_bounds__(256, 1)
void lstm_scan_kernel(const float* __restrict__ pre,      // T x 2048
                      const float* __restrict__ Wh,       // 512 x 2048
                      float* __restrict__ hs,             // T x 512
                      float* hg,                          // 2*512 exchange
                      unsigned* flags,                    // NBLK flags (zeroed)
                      int T) {
  __shared__ float4 w4[4][32][64];               // 128 KB: per-wave [k4][lane]
  __shared__ float hl[532];                      // block-shared h, 4x(128+4 pad)

  const int tid = threadIdx.x;
  const int wv = tid >> 6;                       // wave 0..3
  const int l = tid & 63;

  const int q = l >> 2;                          // col within wave, 0..15
  const int qt = l & 3;                          // k-quarter (128 k each)
  const int dq = q >> 2;                         // dim within wave, 0..3
  const int gq = q & 3;                          // gate (i,f,g,o)
  const int d0w = blockIdx.x * 16 + wv * 4;      // wave's first dim
  const int colw = gq * HID + d0w + dq;          // Wh column

  // stage this wave's 16 columns into LDS (once)
  {
    const float* base = Wh + (size_t)(qt * 128) * G4 + colw;
#pragma unroll 4
    for (int j4 = 0; j4 < 32; ++j4) {
      float4 t;
      t.x = base[(size_t)(4 * j4 + 0) * G4];
      t.y = base[(size_t)(4 * j4 + 1) * G4];
      t.z = base[(size_t)(4 * j4 + 2) * G4];
      t.w = base[(size_t)(4 * j4 + 3) * G4];
      w4[wv][j4][l] = t;
    }
  }
  for (int i = tid; i < 532; i += 256) hl[i] = 0.f;  // h_{-1} = 0
  __syncthreads();

  float creg = 0.f;
  bool dead = false;  // meaningful in wave 0 only (uniform there); STICKY

  for (int s = 0; s < T; ++s) {
    // independent of h: prefetch pre-activation (overlaps poll/barrier)
    float pre_v = pre[(size_t)s * G4 + colw];

    if (s > 0) {
      if (wv == 0) {
        if (!dead) {
          int tries = 0;
          for (;;) {
            unsigned f = (l < NBLK)
                ? __hip_atomic_load(&flags[l], __ATOMIC_RELAXED, __HIP_MEMORY_SCOPE_AGENT)
                : 0xFFFFFFFFu;
            if (__all((int)(f >= (unsigned)s))) break;
            if (++tries > DATA_SPIN) { dead = true; break; }
            __builtin_amdgcn_s_sleep(2);  // ~50ns backoff: keep fabric quiet
          }
        }
        asm volatile("" ::: "memory");  // keep h loads below the poll
        // load h_{s-1} (512 floats; lane takes 8) into the shared LDS copy
        const float* src = hg + ((s - 1) & 1) * HID + l * 8;
        float hv[8];
#pragma unroll
        for (int j = 0; j < 8; ++j)
          hv[j] = __hip_atomic_load(src + j, __ATOMIC_RELAXED, __HIP_MEMORY_SCOPE_AGENT);
        const int pp = 8 * l + 4 * (l >> 4);  // +4 pad per 128-segment
#pragma unroll
        for (int j = 0; j < 8; ++j) hl[pp + j] = hv[j];
      }
      __syncthreads();  // waves 1-3 wait here (no traffic); hl now valid
    }

    // dot: this lane's k-quarter of its column (4 indep FMA chains)
    float a0 = 0.f, a1 = 0.f, a2 = 0.f, a3 = 0.f;
    const float* hseg = &hl[132 * qt];
#pragma unroll
    for (int j4 = 0; j4 < 32; ++j4) {
      float4 wv4 = w4[wv][j4][l];
      float4 hv4 = *reinterpret_cast<const float4*>(&hseg[4 * j4]);
      a0 = fmaf(wv4.x, hv4.x, a0);
      a1 = fmaf(wv4.y, hv4.y, a1);
      a2 = fmaf(wv4.z, hv4.z, a2);
      a3 = fmaf(wv4.w, hv4.w, a3);
    }
    float acc = (a0 + a1) + (a2 + a3);
    acc += __shfl_xor(acc, 1);
    acc += __shfl_xor(acc, 2);
    float full = acc + pre_v;

    // gather the 4 gate values for this lane's dim (16-lane group)
    int gbase = (l & 48) | (l & 3);
    float vi = __shfl(full, gbase);
    float vf = __shfl(full, gbase | 4);
    float vg = __shfl(full, gbase | 8);
    float vo = __shfl(full, gbase | 12);

    float si = 1.f / (1.f + __expf(-vi));
    float sf = 1.f / (1.f + __expf(-vf));
    float so = 1.f / (1.f + __expf(-vo));
    creg = sf * creg + si * tanhf(vg);
    float h = so * tanhf(creg);

    if ((l & 15) == 0) {
      int dim = d0w + (l >> 4);
      hs[(size_t)s * HID + dim] = h;
      __hip_atomic_store(hg + (s & 1) * HID + dim, h, __ATOMIC_RELAXED,
                         __HIP_MEMORY_SCOPE_AGENT);
    }
    __syncthreads();  // all 4 waves' h stores drained (vmcnt) before barrier
    if (tid == 0)
      __hip_atomic_store(&flags[blockIdx.x], (unsigned)(s + 1), __ATOMIC_RELAXED,
                         __HIP_MEMORY_SCOPE_AGENT);
  }
}

// ----------------------------------------------------------------------------
// argmax over 151 logits per row (first-occurrence semantics), one wave per row
// ----------------------------------------------------------------------------
__global__ void argmax_kernel(const float* __restrict__ dists, int* __restrict__ pred_i,
                              float* __restrict__ pred_f) {
  int r = blockIdx.x;
  int lane = threadIdx.x;
  float bv = -3.4e38f;
  int bi = NUM_CLASSES;
  for (int cc = lane; cc < NUM_CLASSES; cc += 64) {
    float v = dists[(size_t)r * NUM_CLASSES + cc];
    if (v > bv) { bv = v; bi = cc; }
  }
  for (int off = 32; off; off >>= 1) {
    float ov = __shfl_xor(bv, off);
    int oi = __shfl_xor(bi, off);
    if (ov > bv || (ov == bv && oi < bi)) { bv = ov; bi = oi; }
  }
  if (lane == 0) {
    pred_i[r] = bi;
    pred_f[r] = (float)bi;
  }
}

// edge_feats[r] = [embed2[pred[r]] | x[r] | enc[r]] (r<2048) else virtual_edge[r-2048]
__global__ void build_edge_kernel(const float* __restrict__ embed2, const int* __restrict__ pred,
                                  const float* __restrict__ x, const float* __restrict__ enc,
                                  const float* __restrict__ vedge, float* __restrict__ out) {
  int r = blockIdx.x;
  float* dst = out + (size_t)r * EDGE_IN;
  if (r >= N_OBJ) {
    const float* src = vedge + (size_t)(r - N_OBJ) * EDGE_IN;
    for (int cc = threadIdx.x; cc < EDGE_IN; cc += blockDim.x) dst[cc] = src[cc];
  } else {
    const float* e = embed2 + (size_t)pred[r] * EMBED;
    for (int cc = threadIdx.x; cc < EMBED; cc += blockDim.x) dst[cc] = e[cc];
    const float* xr = x + (size_t)r * OBJ_DIM;
    for (int cc = threadIdx.x; cc < OBJ_DIM; cc += blockDim.x) dst[EMBED + cc] = xr[cc];
    const float* er = enc + (size_t)r * HID;
    for (int cc = threadIdx.x; cc < HID; cc += blockDim.x) dst[EMBED + OBJ_DIM + cc] = er[cc];
  }
}

// ----------------------------------------------------------------------------
extern "C" void kernel_launch(void* const* d_in, const int* in_sizes, int n_in,
                              void* d_out, int out_size, void* d_ws, size_t ws_size,
                              hipStream_t stream) {
  const float* x        = (const float*)d_in[0];
  const float* odists   = (const float*)d_in[1];
  const float* box      = (const float*)d_in[2];
  const float* vobj     = (const float*)d_in[3];
  const float* vedge    = (const float*)d_in[4];
  const float* embed1   = (const float*)d_in[5];
  const float* embed2   = (const float*)d_in[6];
  const float* pos_W1   = (const float*)d_in[7];
  const float* pos_b1   = (const float*)d_in[8];
  const float* bn_gamma = (const float*)d_in[9];
  const float* bn_beta  = (const float*)d_in[10];
  const float* bn_mean  = (const float*)d_in[11];
  const float* bn_var   = (const float*)d_in[12];
  const float* pos_W2   = (const float*)d_in[13];
  const float* pos_b2   = (const float*)d_in[14];
  const float* obj_Wi   = (const float*)d_in[15];
  const float* obj_Wh   = (const float*)d_in[16];
  const float* obj_b    = (const float*)d_in[17];
  const float* dec_Wi   = (const float*)d_in[18];
  const float* dec_Wh   = (const float*)d_in[19];
  const float* dec_b    = (const float*)d_in[20];
  const float* out_W    = (const float*)d_in[21];
  const float* out_b    = (const float*)d_in[22];
  const float* edge_Wi  = (const float*)d_in[23];
  const float* edge_Wh  = (const float*)d_in[24];
  const float* edge_b   = (const float*)d_in[25];

  float* out = (float*)d_out;

  // workspace layout — edgeh aliases dech (logits GEMM completes first)
  float* bigA = (float*)d_ws;                           // 2064x4808 max
  float* pre  = bigA + (size_t)N_TOT * EDGE_IN;         // 2064x2048
  float* enc  = pre + (size_t)N_TOT * G4;               // 2064x512
  float* dech = enc + (size_t)N_TOT * HID;              // 2064x512 (also edgeh)
  int* pred_i = (int*)(dech + (size_t)N_TOT * HID);     // 2048
  float* hg3  = (float*)(pred_i + N_OBJ);               // 3 x 2*512 floats
  unsigned* flags3 = (unsigned*)(hg3 + 3 * 2 * HID);    // 3 x NBLK

  const int SYNC_U32 = 3 * 2 * HID + 3 * NBLK;          // hg3 + flags3 as u32
  const size_t need_bytes =
      ((size_t)N_TOT * EDGE_IN + (size_t)N_TOT * G4 + 2 * (size_t)N_TOT * HID) * 4 +
      (size_t)N_OBJ * 4 + (size_t)SYNC_U32 * 4 + 256;
  if (ws_size < need_bytes) return;  // insufficient scratch: fail loudly, don't corrupt

  const size_t OUT_PRED = (size_t)N_OBJ * NUM_CLASSES;  // 309248
  const size_t OUT_EDGE = OUT_PRED + N_OBJ;             // 311296

  init_sync_kernel<<<8, 256, 0, stream>>>((unsigned*)hg3, SYNC_U32);

  // build feats
  copy_x_kernel<<<(N_OBJ * (OBJ_DIM / 4) + 255) / 256, 256, 0, stream>>>(x, bigA);
  {
    long n4 = (long)16 * OBJ_IN / 4;
    copy4_kernel<<<(unsigned)((n4 + 255) / 256), 256, 0, stream>>>(
        (const float4*)vobj, (float4*)(bigA + (size_t)N_OBJ * OBJ_IN), n4);
  }
  obj_embed_kernel<<<N_OBJ, 256, 0, stream>>>(odists, embed1, bigA);
  pos_kernel<<<N_OBJ, 128, 0, stream>>>(box, pos_W1, pos_b1, bn_gamma, bn_beta, bn_mean,
                                        bn_var, pos_W2, pos_b2, bigA);

  // encoder LSTM
  gemm_kernel<0><<<dim3(32, 33), 256, 0, stream>>>(bigA, OBJ_IN, obj_Wi, G4, obj_b,
                                                   pre, G4, N_TOT, G4, OBJ_IN);
  lstm_scan_kernel<<<NBLK, 256, 0, stream>>>(pre, obj_Wh, enc, hg3 + 0 * 2 * HID,
                                             flags3 + 0 * NBLK, N_TOT);

  // decoder LSTM (input = [feats | enc], done as two GEMMs)
  gemm_kernel<0><<<dim3(32, 33), 256, 0, stream>>>(bigA, OBJ_IN, dec_Wi, G4, dec_b,
                                                   pre, G4, N_TOT, G4, OBJ_IN);
  gemm_kernel<1><<<dim3(32, 33), 256, 0, stream>>>(enc, HID, dec_Wi + (size_t)OBJ_IN * G4, G4,
                                                   nullptr, pre, G4, N_TOT, G4, HID);
  lstm_scan_kernel<<<NBLK, 256, 0, stream>>>(pre, dec_Wh, dech, hg3 + 1 * 2 * HID,
                                             flags3 + 1 * NBLK, N_TOT);

  // logits (rows 0..2047 only) straight into d_out, then argmax
  gemm_kernel<0><<<dim3(3, 32), 256, 0, stream>>>(dech, HID, out_W, NUM_CLASSES, out_b,
                                                  out, NUM_CLASSES, N_OBJ, NUM_CLASSES, HID);
  argmax_kernel<<<N_OBJ, 64, 0, stream>>>(out, pred_i, out + OUT_PRED);

  // edge LSTM (edgeh aliases dech — safe: logits GEMM already consumed dech)
  build_edge_kernel<<<N_TOT, 256, 0, stream>>>(embed2, pred_i, x, enc, vedge, bigA);
  gemm_kernel<0><<<dim3(32, 33), 256, 0, stream>>>(bigA, EDGE_IN, edge_Wi, G4, edge_b,
                                                   pre, G4, N_TOT, G4, EDGE_IN);
  lstm_scan_kernel<<<NBLK, 256, 0, stream>>>(pre, edge_Wh, dech, hg3 + 2 * 2 * HID,
                                             flags3 + 2 * NBLK, N_TOT);

  // edge_ctx = edgeh[:2048] -> d_out
  copy4_kernel<<<1024, 256, 0, stream>>>((const float4*)dech, (float4*)(out + OUT_EDGE),
                                         (long)N_OBJ * HID / 4);
}

// Round 11
// 20393.387 us; speedup vs baseline: 1.5112x; 1.0705x over previous
//
#include <hip/hip_runtime.h>
#include <cstdint>
#include <cstddef>

#define N_OBJ 2048
#define N_TOT 2064
#define NUM_CLASSES 151
#define EMBED 200
#define HID 512
#define OBJ_DIM 4096
#define POS 128
#define OBJ_IN 4424   // 4096+200+128
#define DEC_IN 4936   // 512+4424
#define EDGE_IN 4808  // 200+4096+512
#define G4 2048       // 4*HID
#define NBLK 32       // scan blocks; 4 waves each; block owns 16 h-dims
#define DATA_SPIN 8000

// ----------------------------------------------------------------------------
// utility kernels
// ----------------------------------------------------------------------------
__global__ void init_sync_kernel(unsigned* p, int n) {
  int i = blockIdx.x * blockDim.x + threadIdx.x;
  int stride = gridDim.x * blockDim.x;
  for (; i < n; i += stride) p[i] = 0u;
}

__global__ void copy4_kernel(const float4* __restrict__ src, float4* __restrict__ dst, long n4) {
  long i = blockIdx.x * (long)blockDim.x + threadIdx.x;
  long stride = (long)gridDim.x * blockDim.x;
  for (; i < n4; i += stride) dst[i] = src[i];
}

// feats[r][0:4096] = x[r]
__global__ void copy_x_kernel(const float* __restrict__ x, float* __restrict__ feats) {
  long i = blockIdx.x * (long)blockDim.x + threadIdx.x; // over 2048*1024 float4
  if (i >= (long)N_OBJ * (OBJ_DIM / 4)) return;
  long r = i >> 10, c = i & 1023;
  reinterpret_cast<float4*>(feats + r * (long)OBJ_IN)[c] =
      reinterpret_cast<const float4*>(x + r * (long)OBJ_DIM)[c];
}

// feats[r][4096:4296] = obj_dists_in[r] @ embed1
__global__ void obj_embed_kernel(const float* __restrict__ dists,
                                 const float* __restrict__ embed1,
                                 float* __restrict__ feats) {
  int r = blockIdx.x;
  __shared__ float drow[NUM_CLASSES];
  for (int c = threadIdx.x; c < NUM_CLASSES; c += blockDim.x)
    drow[c] = dists[(size_t)r * NUM_CLASSES + c];
  __syncthreads();
  for (int j = threadIdx.x; j < EMBED; j += blockDim.x) {
    float s = 0.f;
    for (int k = 0; k < NUM_CLASSES; ++k)
      s = fmaf(drow[k], embed1[(size_t)k * EMBED + j], s);
    feats[(size_t)r * OBJ_IN + OBJ_DIM + j] = s;
  }
}

// feats[r][4296:4424] = relu(BN(box@W1+b1)@W2+b2)
__global__ void pos_kernel(const float* __restrict__ box,
                           const float* __restrict__ W1, const float* __restrict__ b1,
                           const float* __restrict__ gamma, const float* __restrict__ beta,
                           const float* __restrict__ mean, const float* __restrict__ var,
                           const float* __restrict__ W2, const float* __restrict__ b2,
                           float* __restrict__ feats) {
  int r = blockIdx.x;
  __shared__ float h[32];
  __shared__ float bx[9];
  if (threadIdx.x < 9) bx[threadIdx.x] = box[(size_t)r * 9 + threadIdx.x];
  __syncthreads();
  if (threadIdx.x < 32) {
    float s = b1[threadIdx.x];
    for (int k = 0; k < 9; ++k) s = fmaf(bx[k], W1[k * 32 + threadIdx.x], s);
    s = (s - mean[threadIdx.x]) * (1.f / sqrtf(var[threadIdx.x] + 1e-5f)) * gamma[threadIdx.x]
        + beta[threadIdx.x];
    h[threadIdx.x] = s;
  }
  __syncthreads();
  int j = threadIdx.x;
  if (j < POS) {
    float s = b2[j];
    for (int k = 0; k < 32; ++k) s = fmaf(h[k], W2[k * POS + j], s);
    feats[(size_t)r * OBJ_IN + OBJ_DIM + EMBED + j] = fmaxf(s, 0.f);
  }
}

// ----------------------------------------------------------------------------
// generic bounds-checked fp32 GEMM: C[M,N](ldc) = A[M,K](lda) @ B[K,N](ldb) (+bias | +=)
// tile 64x64, BK=16, 256 threads, 4x4 per thread
// ----------------------------------------------------------------------------
template <int ACC>
__global__ __launch_bounds__(256)
void gemm_kernel(const float* __restrict__ A, int lda,
                 const float* __restrict__ B, int ldb,
                 const float* __restrict__ bias,
                 float* __restrict__ C, int ldc,
                 int M, int N, int K) {
  __shared__ __align__(16) float As[16][68];
  __shared__ __align__(16) float Bs[16][64];
  const int row0 = blockIdx.y * 64;
  const int col0 = blockIdx.x * 64;
  const int tid = threadIdx.x;
  const int tx = tid & 15, ty = tid >> 4;
  float acc[4][4] = {};

  for (int k0 = 0; k0 < K; k0 += 16) {
#pragma unroll
    for (int l = 0; l < 4; ++l) {
      int idx = tid + l * 256;
      int m = idx >> 4, kk = idx & 15;
      int gm = row0 + m, gk = k0 + kk;
      As[kk][m] = (gm < M && gk < K) ? A[(size_t)gm * lda + gk] : 0.f;
    }
#pragma unroll
    for (int l = 0; l < 4; ++l) {
      int idx = tid + l * 256;
      int kk = idx >> 6, n = idx & 63;
      int gk = k0 + kk, gn = col0 + n;
      Bs[kk][n] = (gk < K && gn < N) ? B[(size_t)gk * ldb + gn] : 0.f;
    }
    __syncthreads();
#pragma unroll
    for (int kk = 0; kk < 16; ++kk) {
      float4 a = *reinterpret_cast<const float4*>(&As[kk][ty * 4]);
      float4 b = *reinterpret_cast<const float4*>(&Bs[kk][tx * 4]);
      acc[0][0] = fmaf(a.x, b.x, acc[0][0]); acc[0][1] = fmaf(a.x, b.y, acc[0][1]);
      acc[0][2] = fmaf(a.x, b.z, acc[0][2]); acc[0][3] = fmaf(a.x, b.w, acc[0][3]);
      acc[1][0] = fmaf(a.y, b.x, acc[1][0]); acc[1][1] = fmaf(a.y, b.y, acc[1][1]);
      acc[1][2] = fmaf(a.y, b.z, acc[1][2]); acc[1][3] = fmaf(a.y, b.w, acc[1][3]);
      acc[2][0] = fmaf(a.z, b.x, acc[2][0]); acc[2][1] = fmaf(a.z, b.y, acc[2][1]);
      acc[2][2] = fmaf(a.z, b.z, acc[2][2]); acc[2][3] = fmaf(a.z, b.w, acc[2][3]);
      acc[3][0] = fmaf(a.w, b.x, acc[3][0]); acc[3][1] = fmaf(a.w, b.y, acc[3][1]);
      acc[3][2] = fmaf(a.w, b.z, acc[3][2]); acc[3][3] = fmaf(a.w, b.w, acc[3][3]);
    }
    __syncthreads();
  }
#pragma unroll
  for (int i = 0; i < 4; ++i) {
    int gm = row0 + ty * 4 + i;
    if (gm >= M) continue;
#pragma unroll
    for (int j = 0; j < 4; ++j) {
      int gn = col0 + tx * 4 + j;
      if (gn >= N) continue;
      size_t o = (size_t)gm * ldc + gn;
      if (ACC) C[o] += acc[i][j];
      else C[o] = acc[i][j] + (bias ? bias[gn] : 0.f);
    }
  }
}

// ----------------------------------------------------------------------------
// persistent LSTM scan: 32 blocks x 4 waves (R7 geometry, weights in LDS)
// + R5's PROVEN tagged-pair exchange (8-byte atomic {tag=s+1, h}).
// The tag travels WITH the data in one naturally-aligned 8B qword -> no
// producer vmcnt drain, no flag store, no separate h load: producers
// fire-and-forget; wave 0 polls the 64 qwords of buffer (s-1)&1 (8x dwordx2
// per lane, s_sleep(2) backoff, 1 poller/block = R7's congestion discipline),
// fills block-shared LDS, one barrier, compute.
// Lap-safety: a block stores tag s+2 into buffer (s-1)&1 only after its poll
// saw ALL 512 dims of buffer s&1 tagged >= s+1 (incl. every other block's
// step-s store) -> no block laps a still-polling peer.
// Bounded spin + sticky dead-latch: worst case loud absmax fail, never hang.
// All sync via __hip_atomic relaxed/agent — the only codegen path proven
// correct AND non-wedging on this setup (R2/R5/R7).
// ----------------------------------------------------------------------------
__global__ __launch_bounds__(256, 1)
void lstm_scan_kernel(const float* __restrict__ pre,      // T x 2048
                      const float* __restrict__ Wh,       // 512 x 2048
                      float* __restrict__ hs,             // T x 512
                      unsigned long long* hg,             // 2*512 tagged pairs
                      int T) {
  __shared__ float4 w4[4][32][64];               // 128 KB: per-wave [k4][lane]
  __shared__ float hl[532];                      // block-shared h, 4x(128+4 pad)

  const int tid = threadIdx.x;
  const int wv = tid >> 6;                       // wave 0..3
  const int l = tid & 63;

  const int q = l >> 2;                          // col within wave, 0..15
  const int qt = l & 3;                          // k-quarter (128 k each)
  const int dq = q >> 2;                         // dim within wave, 0..3
  const int gq = q & 3;                          // gate (i,f,g,o)
  const int d0w = blockIdx.x * 16 + wv * 4;      // wave's first dim
  const int colw = gq * HID + d0w + dq;          // Wh column

  // stage this wave's 16 columns into LDS (once)
  {
    const float* base = Wh + (size_t)(qt * 128) * G4 + colw;
#pragma unroll 4
    for (int j4 = 0; j4 < 32; ++j4) {
      float4 t;
      t.x = base[(size_t)(4 * j4 + 0) * G4];
      t.y = base[(size_t)(4 * j4 + 1) * G4];
      t.z = base[(size_t)(4 * j4 + 2) * G4];
      t.w = base[(size_t)(4 * j4 + 3) * G4];
      w4[wv][j4][l] = t;
    }
  }
  for (int i = tid; i < 532; i += 256) hl[i] = 0.f;  // h_{-1} = 0
  __syncthreads();

  float creg = 0.f;
  bool dead = false;  // wave-0 only (uniform there); STICKY

  for (int s = 0; s < T; ++s) {
    // independent of h: prefetch pre-activation (overlaps poll/barrier)
    float pre_v = pre[(size_t)s * G4 + colw];

    if (s > 0) {
      if (wv == 0) {
        // poll the tagged pairs of buffer (s-1)&1: lane l owns dims [8l,8l+8)
        const unsigned long long* src = hg + ((s - 1) & 1) * HID + l * 8;
        unsigned long long pv[8];
        if (!dead) {
          int tries = 0;
          for (;;) {
            unsigned tmin = 0xFFFFFFFFu;
#pragma unroll
            for (int j = 0; j < 8; ++j) {
              pv[j] = __hip_atomic_load(src + j, __ATOMIC_RELAXED,
                                        __HIP_MEMORY_SCOPE_AGENT);
              tmin = min(tmin, (unsigned)(pv[j] >> 32));
            }
            if (__all((int)(tmin >= (unsigned)s))) break;  // snapshot valid (tag+data atomic)
            if (++tries > DATA_SPIN) { dead = true; break; }
            __builtin_amdgcn_s_sleep(2);  // keep the fabric quiet
          }
        }
        if (dead) {
#pragma unroll
          for (int j = 0; j < 8; ++j) pv[j] = 0ull;
        }
        // data already in registers: stage into the shared padded LDS copy
        const int pp = 8 * l + 4 * (l >> 4);  // +4 pad per 128-segment
#pragma unroll
        for (int j = 0; j < 8; ++j) hl[pp + j] = __uint_as_float((unsigned)pv[j]);
      }
      __syncthreads();  // waves 1-3 wait here (no traffic); hl now valid
    }

    // dot: this lane's k-quarter of its column (4 indep FMA chains)
    float a0 = 0.f, a1 = 0.f, a2 = 0.f, a3 = 0.f;
    const float* hseg = &hl[132 * qt];
#pragma unroll
    for (int j4 = 0; j4 < 32; ++j4) {
      float4 wv4 = w4[wv][j4][l];
      float4 hv4 = *reinterpret_cast<const float4*>(&hseg[4 * j4]);
      a0 = fmaf(wv4.x, hv4.x, a0);
      a1 = fmaf(wv4.y, hv4.y, a1);
      a2 = fmaf(wv4.z, hv4.z, a2);
      a3 = fmaf(wv4.w, hv4.w, a3);
    }
    float acc = (a0 + a1) + (a2 + a3);
    acc += __shfl_xor(acc, 1);
    acc += __shfl_xor(acc, 2);
    float full = acc + pre_v;

    // gather the 4 gate values for this lane's dim (16-lane group)
    int gbase = (l & 48) | (l & 3);
    float vi = __shfl(full, gbase);
    float vf = __shfl(full, gbase | 4);
    float vg = __shfl(full, gbase | 8);
    float vo = __shfl(full, gbase | 12);

    float si = 1.f / (1.f + __expf(-vi));
    float sf = 1.f / (1.f + __expf(-vf));
    float so = 1.f / (1.f + __expf(-vo));
    creg = sf * creg + si * tanhf(vg);
    float h = so * tanhf(creg);

    if ((l & 15) == 0) {
      int dim = d0w + (l >> 4);
      hs[(size_t)s * HID + dim] = h;
      unsigned long long pvs =
          ((unsigned long long)(unsigned)(s + 1) << 32) | (unsigned)__float_as_uint(h);
      __hip_atomic_store(hg + (s & 1) * HID + dim, pvs, __ATOMIC_RELAXED,
                         __HIP_MEMORY_SCOPE_AGENT);  // fire-and-forget: tag IS the flag
    }
  }
}

// ----------------------------------------------------------------------------
// argmax over 151 logits per row (first-occurrence semantics), one wave per row
// ----------------------------------------------------------------------------
__global__ void argmax_kernel(const float* __restrict__ dists, int* __restrict__ pred_i,
                              float* __restrict__ pred_f) {
  int r = blockIdx.x;
  int lane = threadIdx.x;
  float bv = -3.4e38f;
  int bi = NUM_CLASSES;
  for (int cc = lane; cc < NUM_CLASSES; cc += 64) {
    float v = dists[(size_t)r * NUM_CLASSES + cc];
    if (v > bv) { bv = v; bi = cc; }
  }
  for (int off = 32; off; off >>= 1) {
    float ov = __shfl_xor(bv, off);
    int oi = __shfl_xor(bi, off);
    if (ov > bv || (ov == bv && oi < bi)) { bv = ov; bi = oi; }
  }
  if (lane == 0) {
    pred_i[r] = bi;
    pred_f[r] = (float)bi;
  }
}

// edge_feats[r] = [embed2[pred[r]] | x[r] | enc[r]] (r<2048) else virtual_edge[r-2048]
__global__ void build_edge_kernel(const float* __restrict__ embed2, const int* __restrict__ pred,
                                  const float* __restrict__ x, const float* __restrict__ enc,
                                  const float* __restrict__ vedge, float* __restrict__ out) {
  int r = blockIdx.x;
  float* dst = out + (size_t)r * EDGE_IN;
  if (r >= N_OBJ) {
    const float* src = vedge + (size_t)(r - N_OBJ) * EDGE_IN;
    for (int cc = threadIdx.x; cc < EDGE_IN; cc += blockDim.x) dst[cc] = src[cc];
  } else {
    const float* e = embed2 + (size_t)pred[r] * EMBED;
    for (int cc = threadIdx.x; cc < EMBED; cc += blockDim.x) dst[cc] = e[cc];
    const float* xr = x + (size_t)r * OBJ_DIM;
    for (int cc = threadIdx.x; cc < OBJ_DIM; cc += blockDim.x) dst[EMBED + cc] = xr[cc];
    const float* er = enc + (size_t)r * HID;
    for (int cc = threadIdx.x; cc < HID; cc += blockDim.x) dst[EMBED + OBJ_DIM + cc] = er[cc];
  }
}

// ----------------------------------------------------------------------------
extern "C" void kernel_launch(void* const* d_in, const int* in_sizes, int n_in,
                              void* d_out, int out_size, void* d_ws, size_t ws_size,
                              hipStream_t stream) {
  const float* x        = (const float*)d_in[0];
  const float* odists   = (const float*)d_in[1];
  const float* box      = (const float*)d_in[2];
  const float* vobj     = (const float*)d_in[3];
  const float* vedge    = (const float*)d_in[4];
  const float* embed1   = (const float*)d_in[5];
  const float* embed2   = (const float*)d_in[6];
  const float* pos_W1   = (const float*)d_in[7];
  const float* pos_b1   = (const float*)d_in[8];
  const float* bn_gamma = (const float*)d_in[9];
  const float* bn_beta  = (const float*)d_in[10];
  const float* bn_mean  = (const float*)d_in[11];
  const float* bn_var   = (const float*)d_in[12];
  const float* pos_W2   = (const float*)d_in[13];
  const float* pos_b2   = (const float*)d_in[14];
  const float* obj_Wi   = (const float*)d_in[15];
  const float* obj_Wh   = (const float*)d_in[16];
  const float* obj_b    = (const float*)d_in[17];
  const float* dec_Wi   = (const float*)d_in[18];
  const float* dec_Wh   = (const float*)d_in[19];
  const float* dec_b    = (const float*)d_in[20];
  const float* out_W    = (const float*)d_in[21];
  const float* out_b    = (const float*)d_in[22];
  const float* edge_Wi  = (const float*)d_in[23];
  const float* edge_Wh  = (const float*)d_in[24];
  const float* edge_b   = (const float*)d_in[25];

  float* out = (float*)d_out;

  // workspace layout — edgeh aliases dech (logits GEMM completes first)
  float* bigA = (float*)d_ws;                           // 2064x4808 max
  float* pre  = bigA + (size_t)N_TOT * EDGE_IN;         // 2064x2048
  float* enc  = pre + (size_t)N_TOT * G4;               // 2064x512
  float* dech = enc + (size_t)N_TOT * HID;              // 2064x512 (also edgeh)
  int* pred_i = (int*)(dech + (size_t)N_TOT * HID);     // 2048
  unsigned long long* hg3 = (unsigned long long*)(pred_i + N_OBJ);  // 3 x 1024 pairs

  const int SYNC_U32 = 3 * 2 * HID * 2;                 // hg3 as u32
  const size_t need_bytes =
      ((size_t)N_TOT * EDGE_IN + (size_t)N_TOT * G4 + 2 * (size_t)N_TOT * HID) * 4 +
      (size_t)N_OBJ * 4 + (size_t)SYNC_U32 * 4 + 256;
  if (ws_size < need_bytes) return;  // insufficient scratch: fail loudly, don't corrupt

  const size_t OUT_PRED = (size_t)N_OBJ * NUM_CLASSES;  // 309248
  const size_t OUT_EDGE = OUT_PRED + N_OBJ;             // 311296

  init_sync_kernel<<<8, 256, 0, stream>>>((unsigned*)hg3, SYNC_U32);

  // build feats
  copy_x_kernel<<<(N_OBJ * (OBJ_DIM / 4) + 255) / 256, 256, 0, stream>>>(x, bigA);
  {
    long n4 = (long)16 * OBJ_IN / 4;
    copy4_kernel<<<(unsigned)((n4 + 255) / 256), 256, 0, stream>>>(
        (const float4*)vobj, (float4*)(bigA + (size_t)N_OBJ * OBJ_IN), n4);
  }
  obj_embed_kernel<<<N_OBJ, 256, 0, stream>>>(odists, embed1, bigA);
  pos_kernel<<<N_OBJ, 128, 0, stream>>>(box, pos_W1, pos_b1, bn_gamma, bn_beta, bn_mean,
                                        bn_var, pos_W2, pos_b2, bigA);

  // encoder LSTM
  gemm_kernel<0><<<dim3(32, 33), 256, 0, stream>>>(bigA, OBJ_IN, obj_Wi, G4, obj_b,
                                                   pre, G4, N_TOT, G4, OBJ_IN);
  lstm_scan_kernel<<<NBLK, 256, 0, stream>>>(pre, obj_Wh, enc, hg3 + 0 * 2 * HID, N_TOT);

  // decoder LSTM (input = [feats | enc], done as two GEMMs)
  gemm_kernel<0><<<dim3(32, 33), 256, 0, stream>>>(bigA, OBJ_IN, dec_Wi, G4, dec_b,
                                                   pre, G4, N_TOT, G4, OBJ_IN);
  gemm_kernel<1><<<dim3(32, 33), 256, 0, stream>>>(enc, HID, dec_Wi + (size_t)OBJ_IN * G4, G4,
                                                   nullptr, pre, G4, N_TOT, G4, HID);
  lstm_scan_kernel<<<NBLK, 256, 0, stream>>>(pre, dec_Wh, dech, hg3 + 1 * 2 * HID, N_TOT);

  // logits (rows 0..2047 only) straight into d_out, then argmax
  gemm_kernel<0><<<dim3(3, 32), 256, 0, stream>>>(dech, HID, out_W, NUM_CLASSES, out_b,
                                                  out, NUM_CLASSES, N_OBJ, NUM_CLASSES, HID);
  argmax_kernel<<<N_OBJ, 64, 0, stream>>>(out, pred_i, out + OUT_PRED);

  // edge LSTM (edgeh aliases dech — safe: logits GEMM already consumed dech)
  build_edge_kernel<<<N_TOT, 256, 0, stream>>>(embed2, pred_i, x, enc, vedge, bigA);
  gemm_kernel<0><<<dim3(32, 33), 256, 0, stream>>>(bigA, EDGE_IN, edge_Wi, G4, edge_b,
                                                   pre, G4, N_TOT, G4, EDGE_IN);
  lstm_scan_kernel<<<NBLK, 256, 0, stream>>>(pre, edge_Wh, dech, hg3 + 2 * 2 * HID, N_TOT);

  // edge_ctx = edgeh[:2048] -> d_out
  copy4_kernel<<<1024, 256, 0, stream>>>((const float4*)dech, (float4*)(out + OUT_EDGE),
                                         (long)N_OBJ * HID / 4);
}